// Round 10
// baseline (483.062 us; speedup 1.0000x reference)
//
#include <hip/hip_runtime.h>
#include <hip/hip_bf16.h>
#include <math.h>

// ---------------- geometry ----------------
#define BATCH   2
#define LQ      4096            // seqlen
#define RTOT    8192            // BATCH*LQ rows
#define DM      1024            // d_model
#define DI      2048            // d_inner
#define NH      32              // heads
#define HD      64              // head dim p
#define DS      128             // d_state n
#define CH      256             // chunk
#define NC      16              // chunks per seq
#define XBC_C   2304            // conv channels
#define ZX_C    4384            // in_proj logical output cols
#define ZXS     4352            // zx row stride (dt cols live only in dtraw)
#define NP1     4608            // padded N for gemm1 B^T (18*256)
#define EPS     1e-5f
#define LOG2E   1.4426950408889634f

typedef __hip_bfloat16 bf16;
typedef __bf16 bf16x8v __attribute__((ext_vector_type(8)));
typedef __bf16 bf16x4v __attribute__((ext_vector_type(4)));
typedef float f32x4v __attribute__((ext_vector_type(4)));

// LDS column-block swizzle (T2): spread row-strided column accesses across
// banks. Applied identically on scalar writes and b128 reads.
#define CSWZ(row, col) ((col) ^ ((((row) >> 3) & 7) << 3))

__device__ __forceinline__ void transpose_tile(
    const float* __restrict__ W, bf16* __restrict__ WT, int K, int N,
    int n0, int k0) {
    __shared__ float t[32][33];
    int tx = threadIdx.x & 31, ty = threadIdx.x >> 5;   // 32 x 8
#pragma unroll
    for (int r = 0; r < 32; r += 8) {
        int k = k0 + ty + r, n = n0 + tx;
        t[ty + r][tx] = (n < N) ? W[(size_t)k * N + n] : 0.f;
    }
    __syncthreads();
#pragma unroll
    for (int r = 0; r < 32; r += 8) {
        int n = n0 + ty + r, k = k0 + tx;
        WT[(size_t)n * K + k] = __float2bfloat16(t[tx][ty + r]);
    }
}

// ---------------- F1: add+rmsnorm (wave-per-row), plus in_proj transposes ----
__global__ __launch_bounds__(256) void fused_pre_kernel(
    const float* __restrict__ hid, const float* __restrict__ resid,
    const float* __restrict__ w, float* __restrict__ res_out,
    bf16* __restrict__ h_out, const float* __restrict__ in_proj,
    bf16* __restrict__ Bt1) {
    int bid = blockIdx.x;
    if (bid < RTOT / 4) {
        int wave = threadIdx.x >> 6, lane = threadIdx.x & 63;
        int r = bid * 4 + wave;
        size_t base = (size_t)r * DM;
        float4 s[4];
        float ss = 0.f;
#pragma unroll
        for (int j = 0; j < 4; ++j) {
            int col = lane * 4 + j * 256;
            float4 hv = *(const float4*)&hid[base + col];
            float4 rv = *(const float4*)&resid[base + col];
            s[j] = {hv.x + rv.x, hv.y + rv.y, hv.z + rv.z, hv.w + rv.w};
            *(float4*)&res_out[base + col] = s[j];
            ss += s[j].x * s[j].x + s[j].y * s[j].y +
                  s[j].z * s[j].z + s[j].w * s[j].w;
        }
#pragma unroll
        for (int off = 32; off > 0; off >>= 1) ss += __shfl_xor(ss, off, 64);
        float scale = rsqrtf(ss / (float)DM + EPS);
#pragma unroll
        for (int j = 0; j < 4; ++j) {
            int col = lane * 4 + j * 256;
            float4 wv = *(const float4*)&w[col];
            __hip_bfloat162 p0, p1;
            p0.x = __float2bfloat16(s[j].x * scale * wv.x);
            p0.y = __float2bfloat16(s[j].y * scale * wv.y);
            p1.x = __float2bfloat16(s[j].z * scale * wv.z);
            p1.y = __float2bfloat16(s[j].w * scale * wv.w);
            bf16* hp = &h_out[base + col];
            *(__hip_bfloat162*)hp = p0;
            *(__hip_bfloat162*)(hp + 2) = p1;
        }
    } else {
        int t = bid - RTOT / 4;                // [0, 4608)
        transpose_tile(in_proj, Bt1, DM, ZX_C, (t % 144) * 32, (t / 144) * 32);
    }
}

// ---------------- MFMA GEMM, full-tile register prefetch ---------------------
// C[M,N] = A[M,K](bf16,row-major lda) @ Bt[Npad,K]^T. BM=128 fixed.
// 8 waves (2m x 4n), per-wave 64 x (BN/4) output; BK=64.
// KEY CHANGE (R10): ALL 12-16 fragment ds_read_b128 of a K-tile issue up
// front into register banks, then the full MFMA cluster -- NO sched_barriers.
// The compiler's counted lgkmcnt then interleaves reads/MFMA freely (m97
// mechanism); reads age 100-250cyc before first use instead of the prior
// 1-slot (~40-80cyc) lookahead that stalled every slot (the invariant ~25%
// MfmaUtil across R2/R4 schedules).
// SINGLE=0: double-buffered, 1 block/CU; per-tile ledger:
//   [RD+MM] bar [stage(k+2) vmcnt(PER_TILE) | vmcnt(0)] bar
// SINGLE=1: one buffer + launch_bounds(512,4) -> 2 blocks/CU (GEMM2).
#define GFENCE asm volatile("" ::: "memory")
#define GBAR do { GFENCE; __builtin_amdgcn_s_barrier(); GFENCE; } while (0)
#define GWAIT_VM0 asm volatile("s_waitcnt vmcnt(0)" ::: "memory")

template <int BN, int WRITE_F32, int SINGLE>
__global__ __launch_bounds__(512, SINGLE ? 4 : 2) void gemm_tile_kernel(
    const bf16* __restrict__ A, int lda, const bf16* __restrict__ Bt, int ldb,
    void* __restrict__ C, int ldc, int NXT, int K, float* __restrict__ dtraw) {
    constexpr int BM = 128;
    constexpr int NTW = BN / 64;     // n-frags per wave (4 or 2)
    constexpr int AL = BM / 64;      // A stage calls per tile (2)
    constexpr int BL = BN / 64;      // B stage calls per tile (4 or 2)
    constexpr int PT = AL + BL;      // stage calls per tile (6 or 4)
    constexpr int NBUF = SINGLE ? 1 : 2;
    __shared__ __align__(16) bf16 As[NBUF][BM * 64];
    __shared__ __align__(16) bf16 Bs[NBUF][BN * 64];

    const int tid = threadIdx.x;
    const int lane = tid & 63;
    const int wave = tid >> 6;
    const int wm = wave >> 2, wn = wave & 3;
    const int fr = lane & 15, kg = lane >> 4;
    const int s7 = fr & 7;

    // Grouped XCD mapping; requires (grid/8) % NXT == 0.
    const int bid = blockIdx.x;
    const int xcd = bid & 7;
    const int local = bid >> 3;
    const int MPX = ((int)gridDim.x >> 3) / NXT;   // m-tiles per XCD
    const int mtile = xcd * MPX + (local % MPX);
    const int m0 = mtile * BM;
    const int n0 = (local / MPX) * BN;

    const int trow = tid >> 3;
    const int scol = ((tid & 7) ^ (trow & 7)) << 3;   // elements
    const bf16* aSrc = A + (size_t)(m0 + trow) * lda + scol;
    const bf16* bSrc = Bt + (size_t)(n0 + trow) * ldb + scol;

    auto stage_tile = [&](int kt, int buf) {
#pragma unroll
        for (int j = 0; j < AL; ++j)
            __builtin_amdgcn_global_load_lds(
                (const __attribute__((address_space(1))) void*)(
                    aSrc + (size_t)(j * 64) * lda + kt * 64),
                (__attribute__((address_space(3))) void*)(
                    &As[buf][j * 64 * 64 + tid * 8]),
                16, 0, 0);
#pragma unroll
        for (int j = 0; j < BL; ++j)
            __builtin_amdgcn_global_load_lds(
                (const __attribute__((address_space(1))) void*)(
                    bSrc + (size_t)(j * 64) * ldb + kt * 64),
                (__attribute__((address_space(3))) void*)(
                    &Bs[buf][j * 64 * 64 + tid * 8]),
                16, 0, 0);
    };

    f32x4v acc[4][NTW] = {};
    bf16x8v aF[2][4];                // [kk][mt] full-tile A fragments
    bf16x8v bF[2][NTW];              // [kk][nt] full-tile B fragments

    // read ALL fragments of buffer buf, then run ALL MFMAs (compiler
    // schedules counted lgkmcnt interleave; no sched_barriers).
    auto comp_tile = [&](int buf) {
        const bf16* AsB = &As[buf][0];
        const bf16* BsB = &Bs[buf][0];
#pragma unroll
        for (int kk = 0; kk < 2; ++kk)
#pragma unroll
            for (int mt = 0; mt < 4; ++mt)
                aF[kk][mt] = *(const bf16x8v*)&AsB[
                    (wm * 64 + mt * 16 + fr) * 64 +
                    ((((kk << 2) | kg) ^ s7) << 3)];
#pragma unroll
        for (int kk = 0; kk < 2; ++kk)
#pragma unroll
            for (int nt = 0; nt < NTW; ++nt)
                bF[kk][nt] = *(const bf16x8v*)&BsB[
                    (wn * (BN / 4) + nt * 16 + fr) * 64 +
                    ((((kk << 2) | kg) ^ s7) << 3)];
        __builtin_amdgcn_s_setprio(1);
#pragma unroll
        for (int kk = 0; kk < 2; ++kk)
#pragma unroll
            for (int mt = 0; mt < 4; ++mt)
#pragma unroll
                for (int nt = 0; nt < NTW; ++nt)
                    acc[mt][nt] = __builtin_amdgcn_mfma_f32_16x16x32_bf16(
                        aF[kk][mt], bF[kk][nt], acc[mt][nt], 0, 0, 0);
        __builtin_amdgcn_s_setprio(0);
    };

    const int KT = K >> 6;           // 64-wide K-tiles
    if constexpr (SINGLE) {
        for (int kt = 0; kt < KT; ++kt) {
            GBAR;                    // all waves done reading buffer
            stage_tile(kt, 0);
            GWAIT_VM0;
            GBAR;                    // tile landed for all waves
            comp_tile(0);
        }
    } else {
        stage_tile(0, 0);
        stage_tile(1, 1);
        if constexpr (BN == 256)
            asm volatile("s_waitcnt vmcnt(6)" ::: "memory");  // t0 landed
        else
            asm volatile("s_waitcnt vmcnt(4)" ::: "memory");
        GBAR;
        for (int kt = 0; kt < KT; ++kt) {
            comp_tile(kt & 1);
            if (kt == KT - 1) break;
            GBAR;                    // all waves' lgkm drained -> buf free
            if (kt + 2 < KT) {
                stage_tile(kt + 2, kt & 1);
                // drain tile kt+1 exactly (leave kt+2's PT in flight)
                if constexpr (BN == 256)
                    asm volatile("s_waitcnt vmcnt(6)" ::: "memory");
                else
                    asm volatile("s_waitcnt vmcnt(4)" ::: "memory");
            } else {
                GWAIT_VM0;           // no new stage: drain kt+1 fully
            }
            GBAR;                    // buf (kt+1)&1 ready for all waves
        }
    }

    // epilogue
#pragma unroll
    for (int mt = 0; mt < 4; ++mt) {
#pragma unroll
        for (int nt = 0; nt < NTW; ++nt) {
            int gn = n0 + wn * (BN / 4) + nt * 16 + fr;
#pragma unroll
            for (int rg = 0; rg < 4; ++rg) {
                int gm = m0 + wm * 64 + mt * 16 + kg * 4 + rg;
                float v = acc[mt][nt][rg];
                if (WRITE_F32) {
                    ((float*)C)[(size_t)gm * ldc + gn] = v;
                } else {
                    if (gn < 4352)
                        ((bf16*)C)[(size_t)gm * ldc + gn] = __float2bfloat16(v);
                    else if (gn < 4384)
                        dtraw[(size_t)gm * 32 + (gn - 4352)] = v;
                }
            }
        }
    }
}

// ---------------- F2: conv+SiLU blocks, plus dt softplus/cumsum blocks -------
__global__ __launch_bounds__(256) void fused_conv_dt_kernel(
    const bf16* __restrict__ zx, const float* __restrict__ conv_w,
    const float* __restrict__ conv_b, bf16* __restrict__ xBC,
    const float* __restrict__ dtraw, const float* __restrict__ dt_bias,
    const float* __restrict__ A_log, float* __restrict__ dt_bh,
    float* __restrict__ Ac2_bh) {
    int bid = blockIdx.x;
    if (bid < 9216) {
        int idx = bid * 256 + threadIdx.x;       // RTOT*288 total
        int r = idx / 288;
        int o = idx - r * 288;
        int c = o * 8;
        int b = r >> 12, l = r & (LQ - 1);
        float acc[8];
        {
            float4 cb0 = *(const float4*)&conv_b[c];
            float4 cb1 = *(const float4*)&conv_b[c + 4];
            acc[0] = cb0.x; acc[1] = cb0.y; acc[2] = cb0.z; acc[3] = cb0.w;
            acc[4] = cb1.x; acc[5] = cb1.y; acc[6] = cb1.z; acc[7] = cb1.w;
        }
#pragma unroll
        for (int k = 0; k < 4; ++k) {
            int t = l - 3 + k;
            if (t >= 0) {
                bf16x8v xv = *(const bf16x8v*)&zx[(size_t)(b * LQ + t) * ZXS + DI + c];
                float4 w0 = *(const float4*)&conv_w[k * XBC_C + c];
                float4 w1 = *(const float4*)&conv_w[k * XBC_C + c + 4];
                acc[0] = fmaf(w0.x, (float)xv[0], acc[0]);
                acc[1] = fmaf(w0.y, (float)xv[1], acc[1]);
                acc[2] = fmaf(w0.z, (float)xv[2], acc[2]);
                acc[3] = fmaf(w0.w, (float)xv[3], acc[3]);
                acc[4] = fmaf(w1.x, (float)xv[4], acc[4]);
                acc[5] = fmaf(w1.y, (float)xv[5], acc[5]);
                acc[6] = fmaf(w1.z, (float)xv[6], acc[6]);
                acc[7] = fmaf(w1.w, (float)xv[7], acc[7]);
            }
        }
        bf16x8v ov;
#pragma unroll
        for (int j = 0; j < 8; ++j)
            ov[j] = (__bf16)(acc[j] / (1.f + __expf(-acc[j])));
        *(bf16x8v*)&xBC[(size_t)r * XBC_C + c] = ov;
    } else {
        __shared__ float sA[256];
        int b2 = bid - 9216;                    // (b,h,c)
        int c = b2 & 15, h = (b2 >> 4) & 31, b = b2 >> 9;
        int tid = threadIdx.x;
        int l = c * CH + tid;
        int r = b * LQ + l;
        float v = dtraw[(size_t)r * 32 + h] + dt_bias[h];
        float dt = (v > 20.f) ? v : log1pf(expf(v));
        float A = -expf(A_log[h]);
        sA[tid] = dt * A * LOG2E;               // log2-units cumulative decay
        __syncthreads();
        for (int off = 1; off < 256; off <<= 1) {
            float t = (tid >= off) ? sA[tid - off] : 0.f;
            __syncthreads();
            sA[tid] += t;
            __syncthreads();
        }
        size_t o = (size_t)(b * NH + h) * LQ + l;
        dt_bh[o] = dt;
        Ac2_bh[o] = sA[tid];
    }
}

// ---------------- K4a (MFMA): states[p,n] = sum_l xdtd[l,p] * B[l,n] --------
__global__ __launch_bounds__(256) void states_mfma_kernel(
    const bf16* __restrict__ xBC, const float* __restrict__ dt_bh,
    const float* __restrict__ Ac2, bf16* __restrict__ states) {
    __shared__ __align__(16) __bf16 xdT[64][264];    // [p][l], col-swizzled
    __shared__ __align__(16) __bf16 BT[64][264];     // [n_loc][l], col-swizzled
    int bid = blockIdx.x;                          // (b,h,c)
    int c = bid & 15, h = (bid >> 4) & 31, b = bid >> 9;
    int bh = b * NH + h;
    int rch = b * LQ + c * CH;
    int tid = threadIdx.x;
    int wave = tid >> 6, lane = tid & 63;
    int fr = lane & 15, kg = lane >> 4;
    float Ac2last = Ac2[(size_t)bh * LQ + c * CH + (CH - 1)];

    {   // build xdT[p][l] (column scatter -> CSWZ spreads banks)
        int p2 = (tid & 31) * 2;
        int srow = tid >> 5;
        int key = ((p2 >> 3) & 7) << 3;
#pragma unroll 4
        for (int pass = 0; pass < 32; ++pass) {
            int s = pass * 8 + srow;
            float sc = dt_bh[(size_t)bh * LQ + c * CH + s] *
                       exp2f(Ac2last - Ac2[(size_t)bh * LQ + c * CH + s]);
            __hip_bfloat162 xv =
                *(const __hip_bfloat162*)&xBC[(size_t)(rch + s) * XBC_C + h * HD + p2];
            int sx = s ^ key;                     // (p2+1)>>3 == p2>>3 (p2 even)
            xdT[p2][sx]     = (__bf16)(__bfloat162float(xv.x) * sc);
            xdT[p2 + 1][sx] = (__bf16)(__bfloat162float(xv.y) * sc);
        }
    }
    int wm = (wave >> 1) * 32, wn = (wave & 1) * 32;
    size_t base = (size_t)(bh * NC + c) * HD * DS;
    for (int nh = 0; nh < 2; ++nh) {
        __syncthreads();   // xdT ready (iter0) / prior BT reads done (iter1)
        {   // build BT[n_loc][l] = B[l][nh*64 + n_loc]
            int n_oct = tid & 7, lrow = tid >> 3;      // 32 l-rows per pass
#pragma unroll
            for (int pass = 0; pass < 8; ++pass) {
                int l = pass * 32 + lrow;
                int lx = l ^ (n_oct << 3);             // key((n_oct*8+j)) == n_oct
                bf16x8v bv = *(const bf16x8v*)
                    &xBC[(size_t)(rch + l) * XBC_C + DI + nh * 64 + n_oct * 8];
#pragma unroll
                for (int j = 0; j < 8; ++j)
                    BT[n_oct * 8 + j][lx] = bv[j];
            }
        }
        __syncthreads();
        f32x4v acc[2][2] = {};
#pragma unroll
        for (int kb = 0; kb < 8; ++kb) {
            bf16x8v A2[2], B2[2];
#pragma unroll
            for (int i = 0; i < 2; ++i) {
                int row = wm + i * 16 + fr;
                A2[i] = *(const bf16x8v*)&xdT[row][CSWZ(row, kb * 32 + kg * 8)];
            }
#pragma unroll
            for (int j = 0; j < 2; ++j) {
                int row = wn + j * 16 + fr;
                B2[j] = *(const bf16x8v*)&BT[row][CSWZ(row, kb * 32 + kg * 8)];
            }
#pragma unroll
            for (int i = 0; i < 2; ++i)
#pragma unroll
                for (int j = 0; j < 2; ++j)
                    acc[i][j] = __builtin_amdgcn_mfma_f32_16x16x32_bf16(
                        A2[i], B2[j], acc[i][j], 0, 0, 0);
        }
#pragma unroll
        for (int i = 0; i < 2; ++i)
#pragma unroll
            for (int j = 0; j < 2; ++j)
#pragma unroll
                for (int rg = 0; rg < 4; ++rg) {
                    int p = wm + i * 16 + kg * 4 + rg;
                    int n = nh * 64 + wn + j * 16 + fr;
                    states[base + (size_t)p * DS + n] =
                        __float2bfloat16(acc[i][j][rg]);
                }
    }
}

// ---------------- K5: inter-chunk scan, in place (bf16, f32 carry) -----------
__global__ __launch_bounds__(256) void chunk_scan_kernel(
    bf16* __restrict__ states, const float* __restrict__ Ac2) {
    int bh = blockIdx.x >> 3;        // (b,h)
    int sl = blockIdx.x & 7;         // plane slice: 1024 of 8192 (p,n) elems
    int tid = threadIdx.x;
    float carry[4];
#pragma unroll
    for (int j = 0; j < 4; ++j) carry[j] = 0.f;
    for (int c = 0; c < NC; ++c) {
        float dec = exp2f(Ac2[(size_t)bh * LQ + c * CH + (CH - 1)]);
        size_t base = (size_t)(bh * NC + c) * (HD * DS) + sl * 1024;
#pragma unroll
        for (int j = 0; j < 4; ++j) {
            size_t idx = base + tid + j * 256;
            float tmp = __bfloat162float(states[idx]);
            states[idx] = __float2bfloat16(carry[j]);
            carry[j] = carry[j] * dec + tmp;
        }
    }
}

// ---------------- y slab helper: S^T GEMM -> packed P -> P·xdt ---------------
template <int MASKED>
__device__ __forceinline__ void y_slab(
    const bf16* __restrict__ xBC, int rch, int s0, int fr, int kg,
    const float* As_sh, const float* Al, const bf16x8v CA[4][4],
    __bf16 (*Pw)[36], const __bf16 (*xdtT)[264], f32x4v accY[4][4]) {
#pragma unroll
    for (int half = 0; half < 2; ++half) {
        f32x4v Sacc[2][4] = {};
#pragma unroll
        for (int ks = 0; ks < 4; ++ks) {
            bf16x8v SB[2];
#pragma unroll
            for (int st2 = 0; st2 < 2; ++st2)
                SB[st2] = *(const bf16x8v*)&xBC[
                    (size_t)(rch + s0 + half * 32 + st2 * 16 + fr) * XBC_C
                    + DI + ks * 32 + kg * 8];
#pragma unroll
            for (int st2 = 0; st2 < 2; ++st2)
#pragma unroll
                for (int mt = 0; mt < 4; ++mt) {
                    if (MASKED && (half * 2 + st2) > mt) continue;
                    // D[m=s][n=l]: A = B-rows, B = C-rows
                    Sacc[st2][mt] = __builtin_amdgcn_mfma_f32_16x16x32_bf16(
                        SB[st2], CA[mt][ks], Sacc[st2][mt], 0, 0, 0);
                }
        }
#pragma unroll
        for (int st2 = 0; st2 < 2; ++st2) {
            int sblk = half * 2 + st2;
            float4 As4 = *(const float4*)&As_sh[s0 + half * 32 + st2 * 16 + kg * 4];
            float as[4] = {As4.x, As4.y, As4.z, As4.w};
#pragma unroll
            for (int mt = 0; mt < 4; ++mt) {
                bf16x4v pv;
                if (MASKED && sblk > mt) {
                    pv[0] = pv[1] = pv[2] = pv[3] = (__bf16)0.f;
                } else {
#pragma unroll
                    for (int rg = 0; rg < 4; ++rg) {
                        float v = Sacc[st2][mt][rg] * exp2f(Al[mt] - as[rg]);
                        if (MASKED && sblk == mt && (kg * 4 + rg) > fr) v = 0.f;
                        pv[rg] = (__bf16)v;
                    }
                }
                *(bf16x4v*)&Pw[mt * 16 + fr][st2 * 16 + kg * 4] = pv;
            }
        }
        __asm__ volatile("s_waitcnt lgkmcnt(0)" ::: "memory");
        bf16x8v PA[4], XB[4];
#pragma unroll
        for (int mt = 0; mt < 4; ++mt) {
            bf16x4v plo = *(const bf16x4v*)&Pw[mt * 16 + fr][kg * 8];
            bf16x4v phi = *(const bf16x4v*)&Pw[mt * 16 + fr][kg * 8 + 4];
            bf16x8v pa;
#pragma unroll
            for (int j = 0; j < 4; ++j) { pa[j] = plo[j]; pa[4 + j] = phi[j]; }
            PA[mt] = pa;
        }
#pragma unroll
        for (int pt = 0; pt < 4; ++pt) {
            int row = pt * 16 + fr;
            XB[pt] = *(const bf16x8v*)&xdtT[row][
                CSWZ(row, s0 + half * 32 + kg * 8)];
        }
#pragma unroll
        for (int mt = 0; mt < 4; ++mt)
#pragma unroll
            for (int pt = 0; pt < 4; ++pt)
                accY[mt][pt] = __builtin_amdgcn_mfma_f32_16x16x32_bf16(
                    PA[mt], XB[pt], accY[mt][pt], 0, 0, 0);
        __asm__ volatile("s_waitcnt lgkmcnt(0)" ::: "memory");
    }
}

// ---------------- K4b (MFMA): Y = (C·B^T ∘ L)·xdt + 2^Ac2·(C·prev^T) ---------
__global__ __launch_bounds__(256) void y_mfma_kernel(
    const bf16* __restrict__ xBC, const float* __restrict__ dt_bh,
    const float* __restrict__ Ac2, const bf16* __restrict__ prev,
    bf16* __restrict__ yout /* zx+2048, stride ZXS */) {
    __shared__ __align__(16) __bf16 xdtT[64][264];   // [p][s], col-swizzled
    __shared__ __align__(16) __bf16 P[4][64][36];    // per-wave, [l][s-half]
    __shared__ float As_sh[256];
    int bid = blockIdx.x;
    int c = bid & 15, h = (bid >> 4) & 31, b = bid >> 9;
    int bh = b * NH + h;
    int rch = b * LQ + c * CH;
    int tid = threadIdx.x;
    int wave = tid >> 6, lane = tid & 63;
    int fr = lane & 15, kg = lane >> 4;

    As_sh[tid] = Ac2[(size_t)bh * LQ + c * CH + tid];
    {   // xdtT[p][s] = x[s][p] * dt[s]
        int p2 = (tid & 31) * 2;
        int srow = tid >> 5;
        int key = ((p2 >> 3) & 7) << 3;
#pragma unroll 4
        for (int pass = 0; pass < 32; ++pass) {
            int s = pass * 8 + srow;
            float dtv = dt_bh[(size_t)bh * LQ + c * CH + s];
            __hip_bfloat162 xv =
                *(const __hip_bfloat162*)&xBC[(size_t)(rch + s) * XBC_C + h * HD + p2];
            int sx = s ^ key;
            xdtT[p2][sx]     = (__bf16)(__bfloat162float(xv.x) * dtv);
            xdtT[p2 + 1][sx] = (__bf16)(__bfloat162float(xv.y) * dtv);
        }
    }
    __syncthreads();

    // cache C A-fragments (rows of C) for this wave's strip: [mt][ks]
    bf16x8v CA[4][4];
    {
        size_t rb = (size_t)(rch + wave * 64 + fr) * XBC_C + DI + DS + kg * 8;
#pragma unroll
        for (int mt = 0; mt < 4; ++mt)
#pragma unroll
            for (int ks = 0; ks < 4; ++ks)
                CA[mt][ks] = *(const bf16x8v*)&xBC[rb + (size_t)mt * 16 * XBC_C + ks * 32];
    }

    f32x4v accY[4][4] = {};    // [mt][pt], D[m=l][n=p]

    // off-diagonal: C · prev^T (prev is bf16 -- direct b128 loads)
    {
        size_t pbase = (size_t)(bh * NC + c) * HD * DS;
#pragma unroll
        for (int ks = 0; ks < 4; ++ks) {
            bf16x8v PB[4];
#pragma unroll
            for (int pt = 0; pt < 4; ++pt)
                PB[pt] = *(const bf16x8v*)&prev[
                    pbase + (size_t)(pt * 16 + fr) * DS + ks * 32 + kg * 8];
#pragma unroll
            for (int mt = 0; mt < 4; ++mt)
#pragma unroll
                for (int pt = 0; pt < 4; ++pt)
                    accY[mt][pt] = __builtin_amdgcn_mfma_f32_16x16x32_bf16(
                        CA[mt][ks], PB[pt], accY[mt][pt], 0, 0, 0);
        }
    }
    int l0 = wave * 64;
    // scale off-diag by 2^Ac2[l]  (accY row l = l0 + mt*16 + kg*4 + rg)
#pragma unroll
    for (int mt = 0; mt < 4; ++mt) {
#pragma unroll
        for (int rg = 0; rg < 4; ++rg) {
            float e = exp2f(As_sh[l0 + mt * 16 + kg * 4 + rg]);
#pragma unroll
            for (int pt = 0; pt < 4; ++pt)
                accY[mt][pt][rg] *= e;
        }
    }

    // Al per lane (l = l0 + mt*16 + fr), fixed across st-slabs
    float Al[4];
#pragma unroll
    for (int mt = 0; mt < 4; ++mt) Al[mt] = As_sh[l0 + mt * 16 + fr];

    __bf16 (*Pw)[36] = P[wave];
    for (int st = 0; st < wave; ++st)
        y_slab<0>(xBC, rch, st * 64, fr, kg, As_sh, Al, CA, Pw, xdtT, accY);
    y_slab<1>(xBC, rch, l0, fr, kg, As_sh, Al, CA, Pw, xdtT, accY);

    // epilogue: two 32-col passes staged through P for coalesced stores
#pragma unroll
    for (int ph = 0; ph < 2; ++ph) {
#pragma unroll
        for (int mt = 0; mt < 4; ++mt)
#pragma unroll
            for (int ptl = 0; ptl < 2; ++ptl)
#pragma unroll
                for (int rg = 0; rg < 4; ++rg)
                    Pw[mt * 16 + kg * 4 + rg][ptl * 16 + fr] =
                        (__bf16)accY[mt][ph * 2 + ptl][rg];
        __asm__ volatile("s_waitcnt lgkmcnt(0)" ::: "memory");
        bf16* yp = yout + (size_t)(rch + l0 + lane) * ZXS + h * HD + ph * 32;
#pragma unroll
        for (int q = 0; q < 4; ++q) {
            bf16x4v a = *(const bf16x4v*)&Pw[lane][q * 8];
            bf16x4v bq = *(const bf16x4v*)&Pw[lane][q * 8 + 4];
            bf16x8v v;
#pragma unroll
            for (int j = 0; j < 4; ++j) { v[j] = a[j]; v[4 + j] = bq[j]; }
            *(bf16x8v*)(yp + q * 8) = v;
        }
        __asm__ volatile("s_waitcnt lgkmcnt(0)" ::: "memory");
    }
}

// ---------------- F3: gated RMSNorm (wave-per-row), plus out_proj transposes -
__global__ __launch_bounds__(256) void fused_gate_trans_kernel(
    const bf16* __restrict__ zx, const float* __restrict__ gw,
    const float* __restrict__ Dvec, const bf16* __restrict__ xBC,
    bf16* __restrict__ y /* zx+2048, lda ZXS */,
    const float* __restrict__ out_proj, bf16* __restrict__ Bt2) {
    int bid = blockIdx.x;
    if (bid < RTOT / 4) {
        int wave = threadIdx.x >> 6, lane = threadIdx.x & 63;
        int r = bid * 4 + wave;
        float v[4][8];
        float ss = 0.f;
#pragma unroll
        for (int j = 0; j < 4; ++j) {
            int i0 = lane * 8 + j * 512;
            bf16x8v zv = *(const bf16x8v*)&zx[(size_t)r * ZXS + i0];
            bf16x8v yv = *(const bf16x8v*)&y[(size_t)r * ZXS + i0];
            bf16x8v xv = *(const bf16x8v*)&xBC[(size_t)r * XBC_C + i0];
            float Dh = Dvec[i0 >> 6];            // 8|64 -> head uniform/chunk
#pragma unroll
            for (int k = 0; k < 8; ++k) {
                float z = (float)zv[k];
                float val = ((float)yv[k] + Dh * (float)xv[k]) *
                            (z / (1.f + __expf(-z)));
                v[j][k] = val;
                ss += val * val;
            }
        }
#pragma unroll
        for (int off = 32; off > 0; off >>= 1) ss += __shfl_xor(ss, off, 64);
        float scale = rsqrtf(ss / (float)DI + EPS);
#pragma unroll
        for (int j = 0; j < 4; ++j) {
            int i0 = lane * 8 + j * 512;
            float4 g0 = *(const float4*)&gw[i0];
            float4 g1 = *(const float4*)&gw[i0 + 4];
            float g[8] = {g0.x, g0.y, g0.z, g0.w, g1.x, g1.y, g1.z, g1.w};
            bf16x8v ov;
#pragma unroll
            for (int k = 0; k < 8; ++k)
                ov[k] = (__bf16)(v[j][k] * scale * g[k]);
            *(bf16x8v*)&y[(size_t)r * ZXS + i0] = ov;
        }
    } else {
        int t = bid - RTOT / 4;                // [0, 2048)
        transpose_tile(out_proj, Bt2, DI, DM, (t & 31) * 32, (t >> 5) * 32);
    }
}

// ---------------- launch ----------------
extern "C" void kernel_launch(void* const* d_in, const int* in_sizes, int n_in,
                              void* d_out, int out_size, void* d_ws, size_t ws_size,
                              hipStream_t stream) {
    const float* hid      = (const float*)d_in[0];
    const float* resid    = (const float*)d_in[1];
    const float* norm_w   = (const float*)d_in[2];
    const float* in_proj  = (const float*)d_in[3];
    const float* conv_w   = (const float*)d_in[4];
    const float* conv_b   = (const float*)d_in[5];
    const float* dt_bias  = (const float*)d_in[6];
    const float* A_log    = (const float*)d_in[7];
    const float* Dvec     = (const float*)d_in[8];
    const float* gate_w   = (const float*)d_in[9];
    const float* out_proj = (const float*)d_in[10];

    float* out_p   = (float*)d_out;                  // [8192,1024] f32
    float* res_out = out_p + (size_t)RTOT * DM;      // [8192,1024] f32
    bf16*  h_bf16  = (bf16*)out_p;                   // dead after GEMM1
    bf16*  states  = (bf16*)out_p;                   // 16.8 MB (bf16)

    char* wsb = (char*)d_ws;
    bf16*  zx      = (bf16*)wsb;  wsb += (size_t)RTOT * ZXS * sizeof(bf16);    // 71.3 MB
    bf16*  xBC     = (bf16*)wsb;  wsb += (size_t)RTOT * XBC_C * sizeof(bf16);  // 37.7 MB
    float* dtraw   = (float*)wsb; wsb += (size_t)RTOT * 32 * sizeof(float);    // 1 MB
    float* dt_bh   = (float*)wsb; wsb += (size_t)BATCH * NH * LQ * sizeof(float);
    float* Ac2_bh  = (float*)wsb; wsb += (size_t)BATCH * NH * LQ * sizeof(float);
    wsb += (size_t)1 << 20;   // Bt2 spillover beyond Ac2 (total ~113.3 MB)
    bf16* Bt1 = xBC;                 // aliases xBC front (dead at that time), 9.44 MB
    bf16* Bt2 = (bf16*)dtraw;        // spans dtraw..Ac2+1MB (all dead by F3)

    fused_pre_kernel<<<RTOT / 4 + 4608, 256, 0, stream>>>(
        hid, resid, norm_w, res_out, h_bf16, in_proj, Bt1);
    // GEMM1: 8192 x 4608(pad) x 1024, BM=128 BN=256 -> 1152 blocks, dbuf
    gemm_tile_kernel<256, 0, 0><<<1152, 512, 0, stream>>>(
        h_bf16, DM, Bt1, DM, zx, ZXS, 18, DM, dtraw);
    fused_conv_dt_kernel<<<9216 + 1024, 256, 0, stream>>>(
        zx, conv_w, conv_b, xBC, dtraw, dt_bias, A_log, dt_bh, Ac2_bh);
    states_mfma_kernel<<<BATCH * NH * NC, 256, 0, stream>>>(
        xBC, dt_bh, Ac2_bh, states);
    chunk_scan_kernel<<<BATCH * NH * 8, 256, 0, stream>>>(states, Ac2_bh);
    y_mfma_kernel<<<BATCH * NH * NC, 256, 0, stream>>>(
        xBC, dt_bh, Ac2_bh, states, zx + DI);
    fused_gate_trans_kernel<<<RTOT / 4 + 2048, 256, 0, stream>>>(
        zx, gate_w, Dvec, xBC, zx + DI, out_proj, Bt2);
    // GEMM2: 8192 x 1024 x 2048, BM=128 BN=128 -> 512 blocks (2/CU), single
    gemm_tile_kernel<128, 1, 1><<<512, 512, 0, stream>>>(
        zx + DI, ZXS, Bt2, DI, out_p, DM, 8, DI, nullptr);
}

// Round 11
// 440.089 us; speedup vs baseline: 1.0976x; 1.0976x over previous
//
#include <hip/hip_runtime.h>
#include <hip/hip_bf16.h>
#include <math.h>

// ---------------- geometry ----------------
#define BATCH   2
#define LQ      4096            // seqlen
#define RTOT    8192            // BATCH*LQ rows
#define DM      1024            // d_model
#define DI      2048            // d_inner
#define NH      32              // heads
#define HD      64              // head dim p
#define DS      128             // d_state n
#define CH      256             // chunk
#define NC      16              // chunks per seq
#define XBC_C   2304            // conv channels
#define ZX_C    4384            // in_proj logical output cols
#define ZXS     4352            // zx row stride (dt cols live only in dtraw)
#define NP1     4608            // padded N for gemm1 B^T
#define EPS     1e-5f
#define LOG2E   1.4426950408889634f

typedef __hip_bfloat16 bf16;
typedef __bf16 bf16x8v __attribute__((ext_vector_type(8)));
typedef __bf16 bf16x4v __attribute__((ext_vector_type(4)));
typedef float f32x4v __attribute__((ext_vector_type(4)));

// LDS column-block swizzle (T2): spread row-strided column accesses across
// banks. Applied identically on scalar writes and b128 reads.
#define CSWZ(row, col) ((col) ^ ((((row) >> 3) & 7) << 3))

__device__ __forceinline__ void transpose_tile(
    const float* __restrict__ W, bf16* __restrict__ WT, int K, int N,
    int n0, int k0) {
    __shared__ float t[32][33];
    int tx = threadIdx.x & 31, ty = threadIdx.x >> 5;   // 32 x 8
#pragma unroll
    for (int r = 0; r < 32; r += 8) {
        int k = k0 + ty + r, n = n0 + tx;
        t[ty + r][tx] = (n < N) ? W[(size_t)k * N + n] : 0.f;
    }
    __syncthreads();
#pragma unroll
    for (int r = 0; r < 32; r += 8) {
        int n = n0 + ty + r, k = k0 + tx;
        WT[(size_t)n * K + k] = __float2bfloat16(t[tx][ty + r]);
    }
}

// ---------------- F1: add+rmsnorm (wave-per-row), plus in_proj transposes ----
__global__ __launch_bounds__(256) void fused_pre_kernel(
    const float* __restrict__ hid, const float* __restrict__ resid,
    const float* __restrict__ w, float* __restrict__ res_out,
    bf16* __restrict__ h_out, const float* __restrict__ in_proj,
    bf16* __restrict__ Bt1) {
    int bid = blockIdx.x;
    if (bid < RTOT / 4) {
        int wave = threadIdx.x >> 6, lane = threadIdx.x & 63;
        int r = bid * 4 + wave;
        size_t base = (size_t)r * DM;
        float4 s[4];
        float ss = 0.f;
#pragma unroll
        for (int j = 0; j < 4; ++j) {
            int col = lane * 4 + j * 256;
            float4 hv = *(const float4*)&hid[base + col];
            float4 rv = *(const float4*)&resid[base + col];
            s[j] = {hv.x + rv.x, hv.y + rv.y, hv.z + rv.z, hv.w + rv.w};
            *(float4*)&res_out[base + col] = s[j];
            ss += s[j].x * s[j].x + s[j].y * s[j].y +
                  s[j].z * s[j].z + s[j].w * s[j].w;
        }
#pragma unroll
        for (int off = 32; off > 0; off >>= 1) ss += __shfl_xor(ss, off, 64);
        float scale = rsqrtf(ss / (float)DM + EPS);
#pragma unroll
        for (int j = 0; j < 4; ++j) {
            int col = lane * 4 + j * 256;
            float4 wv = *(const float4*)&w[col];
            __hip_bfloat162 p0, p1;
            p0.x = __float2bfloat16(s[j].x * scale * wv.x);
            p0.y = __float2bfloat16(s[j].y * scale * wv.y);
            p1.x = __float2bfloat16(s[j].z * scale * wv.z);
            p1.y = __float2bfloat16(s[j].w * scale * wv.w);
            bf16* hp = &h_out[base + col];
            *(__hip_bfloat162*)hp = p0;
            *(__hip_bfloat162*)(hp + 2) = p1;
        }
    } else {
        int t = bid - RTOT / 4;                // [0, 4608)
        transpose_tile(in_proj, Bt1, DM, ZX_C, (t % 144) * 32, (t / 144) * 32);
    }
}

// ---------------- MFMA GEMM, full-tile register prefetch ---------------------
// C[M,N] = A[M,K](bf16,row-major lda) @ Bt[Npad,K]^T. BM=128 fixed.
// 8 waves (2m x 4n), per-wave 64 x (BN/4) output; BK=64.
// R11 GEMM1 config: BN=192 double-buffered = 80KB LDS -> 2 blocks/CU at
// launch_bounds(512,4). First config combining ASYNC staging (dbuf) with
// CROSS-BLOCK fill (m114): VGPR est 119 < 128 cap (acc 48 + aF 32 + bF 24);
// grid 1536 = exactly 6/CU -> zero tail. Spill guard: WRITE_SIZE ~70MB.
// SINGLE=1 (GEMM2): one buffer, per-tile {bar;stage;vmcnt0;bar;comp}, 2/CU.
#define GFENCE asm volatile("" ::: "memory")
#define GBAR do { GFENCE; __builtin_amdgcn_s_barrier(); GFENCE; } while (0)
#define GWAIT_VM0 asm volatile("s_waitcnt vmcnt(0)" ::: "memory")

template <int BN, int WRITE_F32, int SINGLE, int OCC>
__global__ __launch_bounds__(512, OCC) void gemm_tile_kernel(
    const bf16* __restrict__ A, int lda, const bf16* __restrict__ Bt, int ldb,
    void* __restrict__ C, int ldc, int NXT, int K, float* __restrict__ dtraw) {
    constexpr int BM = 128;
    constexpr int NTW = BN / 64;     // n-frags per wave (4, 3 or 2)
    constexpr int AL = BM / 64;      // A stage calls per tile (2)
    constexpr int BL = BN / 64;      // B stage calls per tile
    constexpr int PT = AL + BL;      // stage calls per tile
    constexpr int NBUF = SINGLE ? 1 : 2;
    __shared__ __align__(16) bf16 As[NBUF][BM * 64];
    __shared__ __align__(16) bf16 Bs[NBUF][BN * 64];

    const int tid = threadIdx.x;
    const int lane = tid & 63;
    const int wave = tid >> 6;
    const int wm = wave >> 2, wn = wave & 3;
    const int fr = lane & 15, kg = lane >> 4;
    const int s7 = fr & 7;

    // Grouped XCD mapping; requires (grid/8) % NXT == 0.
    const int bid = blockIdx.x;
    const int xcd = bid & 7;
    const int local = bid >> 3;
    const int MPX = ((int)gridDim.x >> 3) / NXT;   // m-tiles per XCD
    const int mtile = xcd * MPX + (local % MPX);
    const int m0 = mtile * BM;
    const int n0 = (local / MPX) * BN;

    const int trow = tid >> 3;
    const int scol = ((tid & 7) ^ (trow & 7)) << 3;   // elements
    const bf16* aSrc = A + (size_t)(m0 + trow) * lda + scol;
    const bf16* bSrc = Bt + (size_t)(n0 + trow) * ldb + scol;

    auto stage_tile = [&](int kt, int buf) {
#pragma unroll
        for (int j = 0; j < AL; ++j)
            __builtin_amdgcn_global_load_lds(
                (const __attribute__((address_space(1))) void*)(
                    aSrc + (size_t)(j * 64) * lda + kt * 64),
                (__attribute__((address_space(3))) void*)(
                    &As[buf][j * 64 * 64 + tid * 8]),
                16, 0, 0);
#pragma unroll
        for (int j = 0; j < BL; ++j)
            __builtin_amdgcn_global_load_lds(
                (const __attribute__((address_space(1))) void*)(
                    bSrc + (size_t)(j * 64) * ldb + kt * 64),
                (__attribute__((address_space(3))) void*)(
                    &Bs[buf][j * 64 * 64 + tid * 8]),
                16, 0, 0);
    };

    // drain all but the newest PT stage calls (tile in flight stays)
    auto wait_prev_tile = [&]() {
        if constexpr (PT == 6)
            asm volatile("s_waitcnt vmcnt(6)" ::: "memory");
        else if constexpr (PT == 5)
            asm volatile("s_waitcnt vmcnt(5)" ::: "memory");
        else
            asm volatile("s_waitcnt vmcnt(4)" ::: "memory");
    };

    f32x4v acc[4][NTW] = {};
    bf16x8v aF[2][4];                // [kk][mt] full-tile A fragments
    bf16x8v bF[2][NTW];              // [kk][nt] full-tile B fragments

    // read ALL fragments of buffer buf, then run ALL MFMAs (compiler
    // schedules counted lgkmcnt interleave; no sched_barriers).
    auto comp_tile = [&](int buf) {
        const bf16* AsB = &As[buf][0];
        const bf16* BsB = &Bs[buf][0];
#pragma unroll
        for (int kk = 0; kk < 2; ++kk)
#pragma unroll
            for (int mt = 0; mt < 4; ++mt)
                aF[kk][mt] = *(const bf16x8v*)&AsB[
                    (wm * 64 + mt * 16 + fr) * 64 +
                    ((((kk << 2) | kg) ^ s7) << 3)];
#pragma unroll
        for (int kk = 0; kk < 2; ++kk)
#pragma unroll
            for (int nt = 0; nt < NTW; ++nt)
                bF[kk][nt] = *(const bf16x8v*)&BsB[
                    (wn * (BN / 4) + nt * 16 + fr) * 64 +
                    ((((kk << 2) | kg) ^ s7) << 3)];
        __builtin_amdgcn_s_setprio(1);
#pragma unroll
        for (int kk = 0; kk < 2; ++kk)
#pragma unroll
            for (int mt = 0; mt < 4; ++mt)
#pragma unroll
                for (int nt = 0; nt < NTW; ++nt)
                    acc[mt][nt] = __builtin_amdgcn_mfma_f32_16x16x32_bf16(
                        aF[kk][mt], bF[kk][nt], acc[mt][nt], 0, 0, 0);
        __builtin_amdgcn_s_setprio(0);
    };

    const int KT = K >> 6;           // 64-wide K-tiles
    if constexpr (SINGLE) {
        for (int kt = 0; kt < KT; ++kt) {
            GBAR;                    // all waves done reading buffer
            stage_tile(kt, 0);
            GWAIT_VM0;
            GBAR;                    // tile landed for all waves
            comp_tile(0);
        }
    } else {
        stage_tile(0, 0);
        stage_tile(1, 1);
        wait_prev_tile();            // tile0 landed (tile1 ages on)
        GBAR;
        for (int kt = 0; kt < KT; ++kt) {
            comp_tile(kt & 1);
            if (kt == KT - 1) break;
            GBAR;                    // all waves' lgkm drained -> buf free
            if (kt + 2 < KT) {
                stage_tile(kt + 2, kt & 1);
                wait_prev_tile();    // drain tile kt+1 exactly
            } else {
                GWAIT_VM0;           // no new stage: drain kt+1 fully
            }
            GBAR;                    // buf (kt+1)&1 ready for all waves
        }
    }

    // epilogue
#pragma unroll
    for (int mt = 0; mt < 4; ++mt) {
#pragma unroll
        for (int nt = 0; nt < NTW; ++nt) {
            int gn = n0 + wn * (BN / 4) + nt * 16 + fr;
#pragma unroll
            for (int rg = 0; rg < 4; ++rg) {
                int gm = m0 + wm * 64 + mt * 16 + kg * 4 + rg;
                float v = acc[mt][nt][rg];
                if (WRITE_F32) {
                    ((float*)C)[(size_t)gm * ldc + gn] = v;
                } else {
                    if (gn < 4352)
                        ((bf16*)C)[(size_t)gm * ldc + gn] = __float2bfloat16(v);
                    else if (gn < 4384)
                        dtraw[(size_t)gm * 32 + (gn - 4352)] = v;
                }
            }
        }
    }
}

// ---------------- F2: conv+SiLU blocks, plus dt softplus/cumsum blocks -------
__global__ __launch_bounds__(256) void fused_conv_dt_kernel(
    const bf16* __restrict__ zx, const float* __restrict__ conv_w,
    const float* __restrict__ conv_b, bf16* __restrict__ xBC,
    const float* __restrict__ dtraw, const float* __restrict__ dt_bias,
    const float* __restrict__ A_log, float* __restrict__ dt_bh,
    float* __restrict__ Ac2_bh) {
    int bid = blockIdx.x;
    if (bid < 9216) {
        int idx = bid * 256 + threadIdx.x;       // RTOT*288 total
        int r = idx / 288;
        int o = idx - r * 288;
        int c = o * 8;
        int b = r >> 12, l = r & (LQ - 1);
        float acc[8];
        {
            float4 cb0 = *(const float4*)&conv_b[c];
            float4 cb1 = *(const float4*)&conv_b[c + 4];
            acc[0] = cb0.x; acc[1] = cb0.y; acc[2] = cb0.z; acc[3] = cb0.w;
            acc[4] = cb1.x; acc[5] = cb1.y; acc[6] = cb1.z; acc[7] = cb1.w;
        }
#pragma unroll
        for (int k = 0; k < 4; ++k) {
            int t = l - 3 + k;
            if (t >= 0) {
                bf16x8v xv = *(const bf16x8v*)&zx[(size_t)(b * LQ + t) * ZXS + DI + c];
                float4 w0 = *(const float4*)&conv_w[k * XBC_C + c];
                float4 w1 = *(const float4*)&conv_w[k * XBC_C + c + 4];
                acc[0] = fmaf(w0.x, (float)xv[0], acc[0]);
                acc[1] = fmaf(w0.y, (float)xv[1], acc[1]);
                acc[2] = fmaf(w0.z, (float)xv[2], acc[2]);
                acc[3] = fmaf(w0.w, (float)xv[3], acc[3]);
                acc[4] = fmaf(w1.x, (float)xv[4], acc[4]);
                acc[5] = fmaf(w1.y, (float)xv[5], acc[5]);
                acc[6] = fmaf(w1.z, (float)xv[6], acc[6]);
                acc[7] = fmaf(w1.w, (float)xv[7], acc[7]);
            }
        }
        bf16x8v ov;
#pragma unroll
        for (int j = 0; j < 8; ++j)
            ov[j] = (__bf16)(acc[j] / (1.f + __expf(-acc[j])));
        *(bf16x8v*)&xBC[(size_t)r * XBC_C + c] = ov;
    } else {
        __shared__ float sA[256];
        int b2 = bid - 9216;                    // (b,h,c)
        int c = b2 & 15, h = (b2 >> 4) & 31, b = b2 >> 9;
        int tid = threadIdx.x;
        int l = c * CH + tid;
        int r = b * LQ + l;
        float v = dtraw[(size_t)r * 32 + h] + dt_bias[h];
        float dt = (v > 20.f) ? v : log1pf(expf(v));
        float A = -expf(A_log[h]);
        sA[tid] = dt * A * LOG2E;               // log2-units cumulative decay
        __syncthreads();
        for (int off = 1; off < 256; off <<= 1) {
            float t = (tid >= off) ? sA[tid - off] : 0.f;
            __syncthreads();
            sA[tid] += t;
            __syncthreads();
        }
        size_t o = (size_t)(b * NH + h) * LQ + l;
        dt_bh[o] = dt;
        Ac2_bh[o] = sA[tid];
    }
}

// ---------------- K4a (MFMA): states[p,n] = sum_l xdtd[l,p] * B[l,n] --------
__global__ __launch_bounds__(256) void states_mfma_kernel(
    const bf16* __restrict__ xBC, const float* __restrict__ dt_bh,
    const float* __restrict__ Ac2, bf16* __restrict__ states) {
    __shared__ __align__(16) __bf16 xdT[64][264];    // [p][l], col-swizzled
    __shared__ __align__(16) __bf16 BT[64][264];     // [n_loc][l], col-swizzled
    int bid = blockIdx.x;                          // (b,h,c)
    int c = bid & 15, h = (bid >> 4) & 31, b = bid >> 9;
    int bh = b * NH + h;
    int rch = b * LQ + c * CH;
    int tid = threadIdx.x;
    int wave = tid >> 6, lane = tid & 63;
    int fr = lane & 15, kg = lane >> 4;
    float Ac2last = Ac2[(size_t)bh * LQ + c * CH + (CH - 1)];

    {   // build xdT[p][l] (column scatter -> CSWZ spreads banks)
        int p2 = (tid & 31) * 2;
        int srow = tid >> 5;
        int key = ((p2 >> 3) & 7) << 3;
#pragma unroll 4
        for (int pass = 0; pass < 32; ++pass) {
            int s = pass * 8 + srow;
            float sc = dt_bh[(size_t)bh * LQ + c * CH + s] *
                       exp2f(Ac2last - Ac2[(size_t)bh * LQ + c * CH + s]);
            __hip_bfloat162 xv =
                *(const __hip_bfloat162*)&xBC[(size_t)(rch + s) * XBC_C + h * HD + p2];
            int sx = s ^ key;                     // (p2+1)>>3 == p2>>3 (p2 even)
            xdT[p2][sx]     = (__bf16)(__bfloat162float(xv.x) * sc);
            xdT[p2 + 1][sx] = (__bf16)(__bfloat162float(xv.y) * sc);
        }
    }
    int wm = (wave >> 1) * 32, wn = (wave & 1) * 32;
    size_t base = (size_t)(bh * NC + c) * HD * DS;
    for (int nh = 0; nh < 2; ++nh) {
        __syncthreads();   // xdT ready (iter0) / prior BT reads done (iter1)
        {   // build BT[n_loc][l] = B[l][nh*64 + n_loc]
            int n_oct = tid & 7, lrow = tid >> 3;      // 32 l-rows per pass
#pragma unroll
            for (int pass = 0; pass < 8; ++pass) {
                int l = pass * 32 + lrow;
                int lx = l ^ (n_oct << 3);             // key((n_oct*8+j)) == n_oct
                bf16x8v bv = *(const bf16x8v*)
                    &xBC[(size_t)(rch + l) * XBC_C + DI + nh * 64 + n_oct * 8];
#pragma unroll
                for (int j = 0; j < 8; ++j)
                    BT[n_oct * 8 + j][lx] = bv[j];
            }
        }
        __syncthreads();
        f32x4v acc[2][2] = {};
#pragma unroll
        for (int kb = 0; kb < 8; ++kb) {
            bf16x8v A2[2], B2[2];
#pragma unroll
            for (int i = 0; i < 2; ++i) {
                int row = wm + i * 16 + fr;
                A2[i] = *(const bf16x8v*)&xdT[row][CSWZ(row, kb * 32 + kg * 8)];
            }
#pragma unroll
            for (int j = 0; j < 2; ++j) {
                int row = wn + j * 16 + fr;
                B2[j] = *(const bf16x8v*)&BT[row][CSWZ(row, kb * 32 + kg * 8)];
            }
#pragma unroll
            for (int i = 0; i < 2; ++i)
#pragma unroll
                for (int j = 0; j < 2; ++j)
                    acc[i][j] = __builtin_amdgcn_mfma_f32_16x16x32_bf16(
                        A2[i], B2[j], acc[i][j], 0, 0, 0);
        }
#pragma unroll
        for (int i = 0; i < 2; ++i)
#pragma unroll
            for (int j = 0; j < 2; ++j)
#pragma unroll
                for (int rg = 0; rg < 4; ++rg) {
                    int p = wm + i * 16 + kg * 4 + rg;
                    int n = nh * 64 + wn + j * 16 + fr;
                    states[base + (size_t)p * DS + n] =
                        __float2bfloat16(acc[i][j][rg]);
                }
    }
}

// ---------------- K5: inter-chunk scan, in place (bf16, f32 carry) -----------
__global__ __launch_bounds__(256) void chunk_scan_kernel(
    bf16* __restrict__ states, const float* __restrict__ Ac2) {
    int bh = blockIdx.x >> 3;        // (b,h)
    int sl = blockIdx.x & 7;         // plane slice: 1024 of 8192 (p,n) elems
    int tid = threadIdx.x;
    float carry[4];
#pragma unroll
    for (int j = 0; j < 4; ++j) carry[j] = 0.f;
    for (int c = 0; c < NC; ++c) {
        float dec = exp2f(Ac2[(size_t)bh * LQ + c * CH + (CH - 1)]);
        size_t base = (size_t)(bh * NC + c) * (HD * DS) + sl * 1024;
#pragma unroll
        for (int j = 0; j < 4; ++j) {
            size_t idx = base + tid + j * 256;
            float tmp = __bfloat162float(states[idx]);
            states[idx] = __float2bfloat16(carry[j]);
            carry[j] = carry[j] * dec + tmp;
        }
    }
}

// ---------------- y slab helper: S^T GEMM -> packed P -> P·xdt ---------------
template <int MASKED>
__device__ __forceinline__ void y_slab(
    const bf16* __restrict__ xBC, int rch, int s0, int fr, int kg,
    const float* As_sh, const float* Al, const bf16x8v CA[4][4],
    __bf16 (*Pw)[36], const __bf16 (*xdtT)[264], f32x4v accY[4][4]) {
#pragma unroll
    for (int half = 0; half < 2; ++half) {
        f32x4v Sacc[2][4] = {};
#pragma unroll
        for (int ks = 0; ks < 4; ++ks) {
            bf16x8v SB[2];
#pragma unroll
            for (int st2 = 0; st2 < 2; ++st2)
                SB[st2] = *(const bf16x8v*)&xBC[
                    (size_t)(rch + s0 + half * 32 + st2 * 16 + fr) * XBC_C
                    + DI + ks * 32 + kg * 8];
#pragma unroll
            for (int st2 = 0; st2 < 2; ++st2)
#pragma unroll
                for (int mt = 0; mt < 4; ++mt) {
                    if (MASKED && (half * 2 + st2) > mt) continue;
                    // D[m=s][n=l]: A = B-rows, B = C-rows
                    Sacc[st2][mt] = __builtin_amdgcn_mfma_f32_16x16x32_bf16(
                        SB[st2], CA[mt][ks], Sacc[st2][mt], 0, 0, 0);
                }
        }
#pragma unroll
        for (int st2 = 0; st2 < 2; ++st2) {
            int sblk = half * 2 + st2;
            float4 As4 = *(const float4*)&As_sh[s0 + half * 32 + st2 * 16 + kg * 4];
            float as[4] = {As4.x, As4.y, As4.z, As4.w};
#pragma unroll
            for (int mt = 0; mt < 4; ++mt) {
                bf16x4v pv;
                if (MASKED && sblk > mt) {
                    pv[0] = pv[1] = pv[2] = pv[3] = (__bf16)0.f;
                } else {
#pragma unroll
                    for (int rg = 0; rg < 4; ++rg) {
                        float v = Sacc[st2][mt][rg] * exp2f(Al[mt] - as[rg]);
                        if (MASKED && sblk == mt && (kg * 4 + rg) > fr) v = 0.f;
                        pv[rg] = (__bf16)v;
                    }
                }
                *(bf16x4v*)&Pw[mt * 16 + fr][st2 * 16 + kg * 4] = pv;
            }
        }
        __asm__ volatile("s_waitcnt lgkmcnt(0)" ::: "memory");
        bf16x8v PA[4], XB[4];
#pragma unroll
        for (int mt = 0; mt < 4; ++mt) {
            bf16x4v plo = *(const bf16x4v*)&Pw[mt * 16 + fr][kg * 8];
            bf16x4v phi = *(const bf16x4v*)&Pw[mt * 16 + fr][kg * 8 + 4];
            bf16x8v pa;
#pragma unroll
            for (int j = 0; j < 4; ++j) { pa[j] = plo[j]; pa[4 + j] = phi[j]; }
            PA[mt] = pa;
        }
#pragma unroll
        for (int pt = 0; pt < 4; ++pt) {
            int row = pt * 16 + fr;
            XB[pt] = *(const bf16x8v*)&xdtT[row][
                CSWZ(row, s0 + half * 32 + kg * 8)];
        }
#pragma unroll
        for (int mt = 0; mt < 4; ++mt)
#pragma unroll
            for (int pt = 0; pt < 4; ++pt)
                accY[mt][pt] = __builtin_amdgcn_mfma_f32_16x16x32_bf16(
                    PA[mt], XB[pt], accY[mt][pt], 0, 0, 0);
        __asm__ volatile("s_waitcnt lgkmcnt(0)" ::: "memory");
    }
}

// ---------------- K4b (MFMA): Y = (C·B^T ∘ L)·xdt + 2^Ac2·(C·prev^T) ---------
__global__ __launch_bounds__(256) void y_mfma_kernel(
    const bf16* __restrict__ xBC, const float* __restrict__ dt_bh,
    const float* __restrict__ Ac2, const bf16* __restrict__ prev,
    bf16* __restrict__ yout /* zx+2048, stride ZXS */) {
    __shared__ __align__(16) __bf16 xdtT[64][264];   // [p][s], col-swizzled
    __shared__ __align__(16) __bf16 P[4][64][36];    // per-wave, [l][s-half]
    __shared__ float As_sh[256];
    int bid = blockIdx.x;
    int c = bid & 15, h = (bid >> 4) & 31, b = bid >> 9;
    int bh = b * NH + h;
    int rch = b * LQ + c * CH;
    int tid = threadIdx.x;
    int wave = tid >> 6, lane = tid & 63;
    int fr = lane & 15, kg = lane >> 4;

    As_sh[tid] = Ac2[(size_t)bh * LQ + c * CH + tid];
    {   // xdtT[p][s] = x[s][p] * dt[s]
        int p2 = (tid & 31) * 2;
        int srow = tid >> 5;
        int key = ((p2 >> 3) & 7) << 3;
#pragma unroll 4
        for (int pass = 0; pass < 32; ++pass) {
            int s = pass * 8 + srow;
            float dtv = dt_bh[(size_t)bh * LQ + c * CH + s];
            __hip_bfloat162 xv =
                *(const __hip_bfloat162*)&xBC[(size_t)(rch + s) * XBC_C + h * HD + p2];
            int sx = s ^ key;
            xdtT[p2][sx]     = (__bf16)(__bfloat162float(xv.x) * dtv);
            xdtT[p2 + 1][sx] = (__bf16)(__bfloat162float(xv.y) * dtv);
        }
    }
    __syncthreads();

    // cache C A-fragments (rows of C) for this wave's strip: [mt][ks]
    bf16x8v CA[4][4];
    {
        size_t rb = (size_t)(rch + wave * 64 + fr) * XBC_C + DI + DS + kg * 8;
#pragma unroll
        for (int mt = 0; mt < 4; ++mt)
#pragma unroll
            for (int ks = 0; ks < 4; ++ks)
                CA[mt][ks] = *(const bf16x8v*)&xBC[rb + (size_t)mt * 16 * XBC_C + ks * 32];
    }

    f32x4v accY[4][4] = {};    // [mt][pt], D[m=l][n=p]

    // off-diagonal: C · prev^T (prev is bf16 -- direct b128 loads)
    {
        size_t pbase = (size_t)(bh * NC + c) * HD * DS;
#pragma unroll
        for (int ks = 0; ks < 4; ++ks) {
            bf16x8v PB[4];
#pragma unroll
            for (int pt = 0; pt < 4; ++pt)
                PB[pt] = *(const bf16x8v*)&prev[
                    pbase + (size_t)(pt * 16 + fr) * DS + ks * 32 + kg * 8];
#pragma unroll
            for (int mt = 0; mt < 4; ++mt)
#pragma unroll
                for (int pt = 0; pt < 4; ++pt)
                    accY[mt][pt] = __builtin_amdgcn_mfma_f32_16x16x32_bf16(
                        CA[mt][ks], PB[pt], accY[mt][pt], 0, 0, 0);
        }
    }
    int l0 = wave * 64;
    // scale off-diag by 2^Ac2[l]  (accY row l = l0 + mt*16 + kg*4 + rg)
#pragma unroll
    for (int mt = 0; mt < 4; ++mt) {
#pragma unroll
        for (int rg = 0; rg < 4; ++rg) {
            float e = exp2f(As_sh[l0 + mt * 16 + kg * 4 + rg]);
#pragma unroll
            for (int pt = 0; pt < 4; ++pt)
                accY[mt][pt][rg] *= e;
        }
    }

    // Al per lane (l = l0 + mt*16 + fr), fixed across st-slabs
    float Al[4];
#pragma unroll
    for (int mt = 0; mt < 4; ++mt) Al[mt] = As_sh[l0 + mt * 16 + fr];

    __bf16 (*Pw)[36] = P[wave];
    for (int st = 0; st < wave; ++st)
        y_slab<0>(xBC, rch, st * 64, fr, kg, As_sh, Al, CA, Pw, xdtT, accY);
    y_slab<1>(xBC, rch, l0, fr, kg, As_sh, Al, CA, Pw, xdtT, accY);

    // epilogue: two 32-col passes staged through P for coalesced stores
#pragma unroll
    for (int ph = 0; ph < 2; ++ph) {
#pragma unroll
        for (int mt = 0; mt < 4; ++mt)
#pragma unroll
            for (int ptl = 0; ptl < 2; ++ptl)
#pragma unroll
                for (int rg = 0; rg < 4; ++rg)
                    Pw[mt * 16 + kg * 4 + rg][ptl * 16 + fr] =
                        (__bf16)accY[mt][ph * 2 + ptl][rg];
        __asm__ volatile("s_waitcnt lgkmcnt(0)" ::: "memory");
        bf16* yp = yout + (size_t)(rch + l0 + lane) * ZXS + h * HD + ph * 32;
#pragma unroll
        for (int q = 0; q < 4; ++q) {
            bf16x4v a = *(const bf16x4v*)&Pw[lane][q * 8];
            bf16x4v bq = *(const bf16x4v*)&Pw[lane][q * 8 + 4];
            bf16x8v v;
#pragma unroll
            for (int j = 0; j < 4; ++j) { v[j] = a[j]; v[4 + j] = bq[j]; }
            *(bf16x8v*)(yp + q * 8) = v;
        }
        __asm__ volatile("s_waitcnt lgkmcnt(0)" ::: "memory");
    }
}

// ---------------- F3: gated RMSNorm (wave-per-row), plus out_proj transposes -
__global__ __launch_bounds__(256) void fused_gate_trans_kernel(
    const bf16* __restrict__ zx, const float* __restrict__ gw,
    const float* __restrict__ Dvec, const bf16* __restrict__ xBC,
    bf16* __restrict__ y /* zx+2048, lda ZXS */,
    const float* __restrict__ out_proj, bf16* __restrict__ Bt2) {
    int bid = blockIdx.x;
    if (bid < RTOT / 4) {
        int wave = threadIdx.x >> 6, lane = threadIdx.x & 63;
        int r = bid * 4 + wave;
        float v[4][8];
        float ss = 0.f;
#pragma unroll
        for (int j = 0; j < 4; ++j) {
            int i0 = lane * 8 + j * 512;
            bf16x8v zv = *(const bf16x8v*)&zx[(size_t)r * ZXS + i0];
            bf16x8v yv = *(const bf16x8v*)&y[(size_t)r * ZXS + i0];
            bf16x8v xv = *(const bf16x8v*)&xBC[(size_t)r * XBC_C + i0];
            float Dh = Dvec[i0 >> 6];            // 8|64 -> head uniform/chunk
#pragma unroll
            for (int k = 0; k < 8; ++k) {
                float z = (float)zv[k];
                float val = ((float)yv[k] + Dh * (float)xv[k]) *
                            (z / (1.f + __expf(-z)));
                v[j][k] = val;
                ss += val * val;
            }
        }
#pragma unroll
        for (int off = 32; off > 0; off >>= 1) ss += __shfl_xor(ss, off, 64);
        float scale = rsqrtf(ss / (float)DI + EPS);
#pragma unroll
        for (int j = 0; j < 4; ++j) {
            int i0 = lane * 8 + j * 512;
            float4 g0 = *(const float4*)&gw[i0];
            float4 g1 = *(const float4*)&gw[i0 + 4];
            float g[8] = {g0.x, g0.y, g0.z, g0.w, g1.x, g1.y, g1.z, g1.w};
            bf16x8v ov;
#pragma unroll
            for (int k = 0; k < 8; ++k)
                ov[k] = (__bf16)(v[j][k] * scale * g[k]);
            *(bf16x8v*)&y[(size_t)r * ZXS + i0] = ov;
        }
    } else {
        int t = bid - RTOT / 4;                // [0, 2048)
        transpose_tile(out_proj, Bt2, DI, DM, (t & 31) * 32, (t >> 5) * 32);
    }
}

// ---------------- launch ----------------
extern "C" void kernel_launch(void* const* d_in, const int* in_sizes, int n_in,
                              void* d_out, int out_size, void* d_ws, size_t ws_size,
                              hipStream_t stream) {
    const float* hid      = (const float*)d_in[0];
    const float* resid    = (const float*)d_in[1];
    const float* norm_w   = (const float*)d_in[2];
    const float* in_proj  = (const float*)d_in[3];
    const float* conv_w   = (const float*)d_in[4];
    const float* conv_b   = (const float*)d_in[5];
    const float* dt_bias  = (const float*)d_in[6];
    const float* A_log    = (const float*)d_in[7];
    const float* Dvec     = (const float*)d_in[8];
    const float* gate_w   = (const float*)d_in[9];
    const float* out_proj = (const float*)d_in[10];

    float* out_p   = (float*)d_out;                  // [8192,1024] f32
    float* res_out = out_p + (size_t)RTOT * DM;      // [8192,1024] f32
    bf16*  h_bf16  = (bf16*)out_p;                   // dead after GEMM1
    bf16*  states  = (bf16*)out_p;                   // 16.8 MB (bf16)

    char* wsb = (char*)d_ws;
    bf16*  zx      = (bf16*)wsb;  wsb += (size_t)RTOT * ZXS * sizeof(bf16);    // 71.3 MB
    bf16*  xBC     = (bf16*)wsb;  wsb += (size_t)RTOT * XBC_C * sizeof(bf16);  // 37.7 MB
    float* dtraw   = (float*)wsb; wsb += (size_t)RTOT * 32 * sizeof(float);    // 1 MB
    float* dt_bh   = (float*)wsb; wsb += (size_t)BATCH * NH * LQ * sizeof(float);
    float* Ac2_bh  = (float*)wsb; wsb += (size_t)BATCH * NH * LQ * sizeof(float);
    wsb += (size_t)1 << 20;   // Bt2 spillover beyond Ac2 (total ~113.3 MB)
    bf16* Bt1 = xBC;                 // aliases xBC front (dead at that time), 9.44 MB
    bf16* Bt2 = (bf16*)dtraw;        // spans dtraw..Ac2+1MB (all dead by F3)

    fused_pre_kernel<<<RTOT / 4 + 4608, 256, 0, stream>>>(
        hid, resid, norm_w, res_out, h_bf16, in_proj, Bt1);
    // GEMM1: 8192 x 4608(pad) x 1024, BM=128 BN=192 -> 64x24 = 1536 blocks,
    // double-buffered 80KB LDS + launch_bounds(512,4) -> 2 blocks/CU,
    // grid exactly 6/CU (zero tail)
    gemm_tile_kernel<192, 0, 0, 4><<<1536, 512, 0, stream>>>(
        h_bf16, DM, Bt1, DM, zx, ZXS, 24, DM, dtraw);
    fused_conv_dt_kernel<<<9216 + 1024, 256, 0, stream>>>(
        zx, conv_w, conv_b, xBC, dtraw, dt_bias, A_log, dt_bh, Ac2_bh);
    states_mfma_kernel<<<BATCH * NH * NC, 256, 0, stream>>>(
        xBC, dt_bh, Ac2_bh, states);
    chunk_scan_kernel<<<BATCH * NH * 8, 256, 0, stream>>>(states, Ac2_bh);
    y_mfma_kernel<<<BATCH * NH * NC, 256, 0, stream>>>(
        xBC, dt_bh, Ac2_bh, states, zx + DI);
    fused_gate_trans_kernel<<<RTOT / 4 + 2048, 256, 0, stream>>>(
        zx, gate_w, Dvec, xBC, zx + DI, out_proj, Bt2);
    // GEMM2: 8192 x 1024 x 2048, BM=128 BN=128 -> 512 blocks (2/CU), single
    gemm_tile_kernel<128, 1, 1, 4><<<512, 512, 0, stream>>>(
        zx + DI, ZXS, Bt2, DI, out_p, DM, 8, DI, nullptr);
}